// Round 1
// baseline (1778.828 us; speedup 1.0000x reference)
//
#include <hip/hip_runtime.h>
#include <math.h>

#define NQ_DEFAULT 8192
#define TOTAL_FEAT 12240
#define NF4 3060           // TOTAL_FEAT / 4
#define KSLICE 765         // 12240 / 16

// center + 6 faces (reference order: center gather, then FACE list)
__constant__ int OFF7[7][3] = {
    {0,0,0},{1,0,0},{-1,0,0},{0,1,0},{0,-1,0},{0,0,1},{0,0,-1}
};
// FACE(6) then CORNER(8) — spatial part of BASIC_ST rows (row r: spat = r>>1, tt = (r&1)? -1:+1)
__constant__ int SPAT14[14][3] = {
    {1,0,0},{-1,0,0},{0,1,0},{0,-1,0},{0,0,1},{0,0,-1},
    {1,1,1},{-1,-1,-1},{1,-1,-1},{-1,1,1},{1,1,-1},{-1,-1,1},{1,-1,1},{-1,1,-1}
};
// CORNER(8) again for EXP_ST (row r: corner = r/11, tt = EXPT[r%11])
__constant__ int CORN8[8][3] = {
    {1,1,1},{-1,-1,-1},{1,-1,-1},{-1,1,1},{1,1,-1},{-1,-1,1},{1,-1,1},{-1,1,-1}
};
__constant__ int EXPT[11] = {-64,-8,-4,-2,-1,0,1,2,4,8,64};

__global__ __launch_bounds__(256)
void st_lookup_kernel(const float* __restrict__ pos, const float* __restrict__ dirv,
                      const float* __restrict__ t,
                      const float* __restrict__ tb0, const float* __restrict__ tb1,
                      const float* __restrict__ tb2, const float* __restrict__ tb3,
                      const float* __restrict__ st1, const float* __restrict__ st2,
                      const float* __restrict__ tf3,
                      const float* __restrict__ rms_scale, const float* __restrict__ w_down,
                      const float* __restrict__ w_final, const float* __restrict__ b_final,
                      float* __restrict__ out)
{
    __shared__ float4 sm4[NF4 + 32];          // 49472 B -> 3 blocks/CU
    float* sx   = (float*)sm4;                // 12240 feature floats (scaled, relu'd)
    float* sred = (float*)(sm4 + NF4);        // 128 floats scratch

    const int q   = blockIdx.x;
    const int tid = threadIdx.x;

    const float px = pos[q*3+0], py = pos[q*3+1], pz = pos[q*3+2];
    const float tv = t[q];

    // scale_idx: trunc(x * (dim-1)), x in [0,1)
    const int b0x = (int)(px*127.f), b0y = (int)(py*127.f), b0z = (int)(pz*127.f);
    const int b1x = (int)(px*63.f),  b1y = (int)(py*63.f),  b1z = (int)(pz*63.f);
    const int b2x = (int)(px*31.f),  b2y = (int)(py*31.f),  b2z = (int)(pz*31.f);
    const int b3x = (int)(px*15.f),  b3y = (int)(py*15.f),  b3z = (int)(pz*15.f);
    // t_idx broadcast quirk: computed vs DIMS_ST1=(16,16,16,64), reused for st2/tf3
    const int i15 = (int)(tv*15.f);
    const int i63 = (int)(tv*63.f);

    const float4* sc4 = (const float4*)rms_scale;
    const float4* t0v = (const float4*)tb0;
    const float4* t1v = (const float4*)tb1;
    const float4* t2v = (const float4*)tb2;
    const float4* t3v = (const float4*)tb3;
    const float4* s1v = (const float4*)st1;
    const float4* s2v = (const float4*)st2;
    const float4* tfv = (const float4*)tf3;

    float ss = 0.f;
    for (int u = tid; u < NF4; u += 256) {
        float4 v;
        if (u < 28) {                       // f0: 7 x 16, dims 128^3
            int l = u >> 2, f = u & 3;
            int ix = (b0x + OFF7[l][0] + 128) & 127;
            int iy = (b0y + OFF7[l][1] + 128) & 127;
            int iz = (b0z + OFF7[l][2] + 128) & 127;
            int idx3 = (ix*128 + iy)*128 + iz;
            v = t0v[idx3*4 + f];
        } else if (u < 140) {               // f1: 7 x 64, dims 64^3
            int uu = u - 28;
            int l = uu >> 4, f = uu & 15;
            int ix = (b1x + OFF7[l][0] + 64) & 63;
            int iy = (b1y + OFF7[l][1] + 64) & 63;
            int iz = (b1z + OFF7[l][2] + 64) & 63;
            int idx3 = (ix*64 + iy)*64 + iz;
            v = t1v[idx3*16 + f];
        } else if (u < 588) {               // f2: 7 x 256, dims 32^3
            int uu = u - 140;
            int l = uu >> 6, f = uu & 63;
            int ix = (b2x + OFF7[l][0] + 32) & 31;
            int iy = (b2y + OFF7[l][1] + 32) & 31;
            int iz = (b2z + OFF7[l][2] + 32) & 31;
            int idx3 = (ix*32 + iy)*32 + iz;
            v = t2v[idx3*64 + f];
        } else if (u < 2380) {              // f3: 7 x 1024, dims 16^3
            int uu = u - 588;
            int l = uu >> 8, f = uu & 255;
            int ix = (b3x + OFF7[l][0] + 16) & 15;
            int iy = (b3y + OFF7[l][1] + 16) & 15;
            int iz = (b3z + OFF7[l][2] + 16) & 15;
            int idx3 = (ix*16 + iy)*16 + iz;
            v = t3v[idx3*256 + f];
        } else if (u < 2828) {              // st1: 28 x 64, dims (16,16,16,64)
            int uu = u - 2380;
            int r = uu >> 4, f = uu & 15;
            int s = r >> 1, tt = (r & 1) ? -1 : 1;
            int ix = (i15 + SPAT14[s][0] + 16) & 15;
            int iy = (i15 + SPAT14[s][1] + 16) & 15;
            int iz = (i15 + SPAT14[s][2] + 16) & 15;
            int it = (i63 + tt + 64) & 63;
            int idx4 = ((ix*16 + iy)*16 + iz)*64 + it;
            v = s1v[idx4*16 + f];
        } else if (u < 2884) {              // st2: 28 x 8, dims (64,64,64,64)
            int uu = u - 2828;
            int r = uu >> 1, f = uu & 1;
            int s = r >> 1, tt = (r & 1) ? -1 : 1;
            int ix = (i15 + SPAT14[s][0] + 64) & 63;
            int iy = (i15 + SPAT14[s][1] + 64) & 63;
            int iz = (i15 + SPAT14[s][2] + 64) & 63;
            int it = (i63 + tt + 64) & 63;
            int idx4 = ((ix*64 + iy)*64 + iz)*64 + it;
            v = s2v[idx4*2 + f];
        } else {                            // tf3: 88 x 8, dims (4,4,4,65536)
            int uu = u - 2884;
            int r = uu >> 1, f = uu & 1;
            int c = r / 11, ti = r - c*11;
            int ix = (i15 + CORN8[c][0] + 4) & 3;
            int iy = (i15 + CORN8[c][1] + 4) & 3;
            int iz = (i15 + CORN8[c][2] + 4) & 3;
            int it = (i63 + EXPT[ti] + 65536) & 65535;
            int idx4 = ((ix*4 + iy)*4 + iz)*65536 + it;
            v = tfv[idx4*2 + f];
        }
        float4 r4;
        r4.x = fmaxf(v.x, 0.f); r4.y = fmaxf(v.y, 0.f);
        r4.z = fmaxf(v.z, 0.f); r4.w = fmaxf(v.w, 0.f);
        ss += r4.x*r4.x + r4.y*r4.y + r4.z*r4.z + r4.w*r4.w;   // norm uses pre-scale relu'd x
        float4 s4 = sc4[u];
        float4 yv;
        yv.x = r4.x*s4.x; yv.y = r4.y*s4.y; yv.z = r4.z*s4.z; yv.w = r4.w*s4.w;
        sm4[u] = yv;
    }

    // sumsq reduction: wave (64) shuffle then cross-wave via LDS
    #pragma unroll
    for (int o = 32; o > 0; o >>= 1) ss += __shfl_down(ss, o, 64);
    const int wid = tid >> 6, lane = tid & 63;
    if (lane == 0) sred[wid] = ss;
    __syncthreads();
    if (tid == 0) {
        float tot = sred[0] + sred[1] + sred[2] + sred[3];
        float rms = sqrtf(tot) * (1.0f / sqrtf((float)TOTAL_FEAT));
        sred[8] = 1.0f / (rms + 1e-8f);
    }
    __syncthreads();
    const float inv = sred[8];

    // phase 3: h[64] = relu(inv * sum_k y[k] * W[k][j])
    // thread (qq = tid>>4, jq = tid&15): k-slice [qq*765, +765), j-quad jq
    const int qq = tid >> 4, jq = tid & 15;
    const float4* wd4 = (const float4*)w_down;
    float4 acc = make_float4(0.f, 0.f, 0.f, 0.f);
    const int k0 = qq * KSLICE;
    #pragma unroll 5
    for (int k = k0; k < k0 + KSLICE; ++k) {
        float xv = sx[k];
        float4 w = wd4[(k << 4) + jq];
        acc.x += xv * w.x; acc.y += xv * w.y; acc.z += xv * w.z; acc.w += xv * w.w;
    }
    __syncthreads();                 // all x reads done; safe to alias sx as scratch
    sx[(jq*4 + 0)*16 + qq] = acc.x;  // layout [j][qq]
    sx[(jq*4 + 1)*16 + qq] = acc.y;
    sx[(jq*4 + 2)*16 + qq] = acc.z;
    sx[(jq*4 + 3)*16 + qq] = acc.w;
    __syncthreads();
    if (tid < 64) {
        float s = 0.f;
        #pragma unroll
        for (int e = 0; e < 16; ++e) s += sx[tid*16 + e];
        sred[16 + tid] = fmaxf(inv * s, 0.f);   // h[j]
    }
    __syncthreads();
    if (tid < 4) {
        float s = b_final[tid];
        #pragma unroll 4
        for (int c = 0; c < 64; ++c) s += sred[16 + c] * w_final[c*4 + tid];
        s += dirv[q*3+0] * w_final[64*4 + tid];
        s += dirv[q*3+1] * w_final[65*4 + tid];
        s += dirv[q*3+2] * w_final[66*4 + tid];
        s += tv          * w_final[67*4 + tid];
        out[q*4 + tid] = 1.0f / (1.0f + expf(-s));
    }
}

extern "C" void kernel_launch(void* const* d_in, const int* in_sizes, int n_in,
                              void* d_out, int out_size, void* d_ws, size_t ws_size,
                              hipStream_t stream) {
    const float* pos  = (const float*)d_in[0];
    const float* dirv = (const float*)d_in[1];
    const float* t    = (const float*)d_in[2];
    const float* tb0  = (const float*)d_in[3];
    const float* tb1  = (const float*)d_in[4];
    const float* tb2  = (const float*)d_in[5];
    const float* tb3  = (const float*)d_in[6];
    const float* st1  = (const float*)d_in[7];
    const float* st2  = (const float*)d_in[8];
    const float* tf3  = (const float*)d_in[9];
    const float* rs   = (const float*)d_in[10];
    const float* wd   = (const float*)d_in[11];
    const float* wf   = (const float*)d_in[12];
    const float* bf   = (const float*)d_in[13];
    float* out = (float*)d_out;

    const int N = in_sizes[2];  // 8192
    st_lookup_kernel<<<dim3(N), dim3(256), 0, stream>>>(
        pos, dirv, t, tb0, tb1, tb2, tb3, st1, st2, tf3, rs, wd, wf, bf, out);
}

// Round 2
// 888.958 us; speedup vs baseline: 2.0010x; 2.0010x over previous
//
#include <hip/hip_runtime.h>
#include <math.h>

#define TOTF   12240
#define NU     3060          // TOTF/4 float4 features
#define KTILE  256
#define NTILES 48            // ceil(12240/256)
#define ASTRIDE 264          // bf16 elems per LDS row (256 + 8 pad, keeps 16B align)
#define MQ     16            // queries per block
#define NTHR   512

typedef float f32x4  __attribute__((ext_vector_type(4)));
typedef short bf16x8 __attribute__((ext_vector_type(8)));

// center + 6 faces (reference order)
__constant__ int OFF7[7][3] = {
    {0,0,0},{1,0,0},{-1,0,0},{0,1,0},{0,-1,0},{0,0,1},{0,0,-1}
};
// FACE(6) then CORNER(8): BASIC_ST row r -> spat = r>>1, tt = (r&1)? -1:+1
__constant__ int SPAT14[14][3] = {
    {1,0,0},{-1,0,0},{0,1,0},{0,-1,0},{0,0,1},{0,0,-1},
    {1,1,1},{-1,-1,-1},{1,-1,-1},{-1,1,1},{1,1,-1},{-1,-1,1},{1,-1,1},{-1,1,-1}
};
__constant__ int CORN8[8][3] = {
    {1,1,1},{-1,-1,-1},{1,-1,-1},{-1,1,1},{1,1,-1},{-1,-1,1},{1,-1,1},{-1,1,-1}
};
__constant__ int EXPT[11] = {-64,-8,-4,-2,-1,0,1,2,4,8,64};

static __device__ __forceinline__ unsigned short f2bf(float f) {
    unsigned int u = __float_as_uint(f);
    u += 0x7fffu + ((u >> 16) & 1u);          // round-to-nearest-even
    return (unsigned short)(u >> 16);
}

// ---- pre-kernel: Wt[j][k] = bf16(w_down[k][j] * rms_scale[k]) --------------
__global__ __launch_bounds__(256)
void wconv_kernel(const float* __restrict__ w, const float* __restrict__ s,
                  unsigned short* __restrict__ Wt) {
    int id = blockIdx.x * 256 + threadIdx.x;
    if (id < TOTF * 64) {
        int k = id >> 6, j = id & 63;
        Wt[j * TOTF + k] = f2bf(w[id] * s[k]);
    }
}

// ---- main fused gather + rmsnorm + GEMM + head -----------------------------
__global__ __launch_bounds__(NTHR)
void st_fused_kernel(const float* __restrict__ pos, const float* __restrict__ dirv,
                     const float* __restrict__ t,
                     const float* __restrict__ tb0, const float* __restrict__ tb1,
                     const float* __restrict__ tb2, const float* __restrict__ tb3,
                     const float* __restrict__ st1, const float* __restrict__ st2,
                     const float* __restrict__ tf3,
                     const unsigned short* __restrict__ Wt,
                     const float* __restrict__ w_final, const float* __restrict__ b_final,
                     float* __restrict__ out, int N)
{
    __shared__ unsigned long long bases_s[172 * MQ];                  // 22016 B
    __shared__ __align__(16) unsigned short Atile[MQ * ASTRIDE];      //  8448 B
    __shared__ __align__(16) unsigned short Wtile[64 * ASTRIDE];      // 33792 B
    __shared__ float ssq_s[MQ];
    __shared__ float inv_s[MQ];

    const int tid = threadIdx.x;
    const int q0  = blockIdx.x * MQ;
    const int q   = tid & 15;            // this thread's query (gather role)
    const int qg  = min(q0 + q, N - 1);

    // ---- phase 0: per-(q,entry) base addresses ----
    {
        const float px = pos[qg*3+0], py = pos[qg*3+1], pz = pos[qg*3+2];
        const float tv = t[qg];
        const int b0x=(int)(px*127.f), b0y=(int)(py*127.f), b0z=(int)(pz*127.f);
        const int b1x=(int)(px*63.f),  b1y=(int)(py*63.f),  b1z=(int)(pz*63.f);
        const int b2x=(int)(px*31.f),  b2y=(int)(py*31.f),  b2z=(int)(pz*31.f);
        const int b3x=(int)(px*15.f),  b3y=(int)(py*15.f),  b3z=(int)(pz*15.f);
        const int i15=(int)(tv*15.f),  i63=(int)(tv*63.f);   // t_idx broadcast quirk

        for (int ent = tid >> 4; ent < 172; ent += 32) {
            unsigned long long a;
            if (ent < 7) {
                int ix=(b0x+OFF7[ent][0]+128)&127, iy=(b0y+OFF7[ent][1]+128)&127, iz=(b0z+OFF7[ent][2]+128)&127;
                a = (unsigned long long)tb0 + (unsigned long long)((ix*128+iy)*128+iz) * 64ull;       // 16 f
            } else if (ent < 14) {
                int l=ent-7;
                int ix=(b1x+OFF7[l][0]+64)&63, iy=(b1y+OFF7[l][1]+64)&63, iz=(b1z+OFF7[l][2]+64)&63;
                a = (unsigned long long)tb1 + (unsigned long long)((ix*64+iy)*64+iz) * 256ull;        // 64 f
            } else if (ent < 21) {
                int l=ent-14;
                int ix=(b2x+OFF7[l][0]+32)&31, iy=(b2y+OFF7[l][1]+32)&31, iz=(b2z+OFF7[l][2]+32)&31;
                a = (unsigned long long)tb2 + (unsigned long long)((ix*32+iy)*32+iz) * 1024ull;       // 256 f
            } else if (ent < 28) {
                int l=ent-21;
                int ix=(b3x+OFF7[l][0]+16)&15, iy=(b3y+OFF7[l][1]+16)&15, iz=(b3z+OFF7[l][2]+16)&15;
                a = (unsigned long long)tb3 + (unsigned long long)((ix*16+iy)*16+iz) * 4096ull;       // 1024 f
            } else if (ent < 56) {
                int r=ent-28, s=r>>1, tt=(r&1)?-1:1;
                int ix=(i15+SPAT14[s][0]+16)&15, iy=(i15+SPAT14[s][1]+16)&15, iz=(i15+SPAT14[s][2]+16)&15;
                int it=(i63+tt+64)&63;
                a = (unsigned long long)st1 + (unsigned long long)(((ix*16+iy)*16+iz)*64+it) * 256ull; // 64 f
            } else if (ent < 84) {
                int r=ent-56, s=r>>1, tt=(r&1)?-1:1;
                int ix=(i15+SPAT14[s][0]+64)&63, iy=(i15+SPAT14[s][1]+64)&63, iz=(i15+SPAT14[s][2]+64)&63;
                int it=(i63+tt+64)&63;
                a = (unsigned long long)st2 + (unsigned long long)(((ix*64+iy)*64+iz)*64+it) * 32ull;  // 8 f
            } else {
                int r=ent-84, c=r/11, ti=r-c*11;
                int ix=(i15+CORN8[c][0]+4)&3, iy=(i15+CORN8[c][1]+4)&3, iz=(i15+CORN8[c][2]+4)&3;
                int it=(i63+EXPT[ti]+65536)&65535;
                a = (unsigned long long)tf3 + (unsigned long long)(((ix*4+iy)*4+iz)*65536+it) * 32ull; // 8 f
            }
            bases_s[ent * MQ + q] = a;
        }
    }
    if (tid < MQ) ssq_s[tid] = 0.f;

    // MFMA roles
    const int lane = tid & 63, w = tid >> 6;
    const int jt = w & 3, ksp = w >> 2;            // 4 j-tiles x 2 K-split halves
    const int mrow = lane & 15, kq = (lane >> 4) * 8;
    f32x4 acc = {0.f, 0.f, 0.f, 0.f};
    float ss = 0.f;

    for (int tile = 0; tile < NTILES; ++tile) {
        __syncthreads();                            // frag reads of prev tile done; bases visible
        // ---- stage A: gather 16 q x 64 float4 (relu, bf16, sumsq) ----
        const int u0 = tile * 64;
        #pragma unroll
        for (int it2 = 0; it2 < 2; ++it2) {
            const int e = ((it2 * NTHR) + tid) >> 4;       // 0..63
            const int u = u0 + e;
            float4 v = make_float4(0.f, 0.f, 0.f, 0.f);
            if (u < NU) {
                int ent, f;
                if (u < 28)        { ent = u >> 2;                 f = u & 3; }
                else if (u < 140)  { int x=u-28;   ent=7 +(x>>4);  f = x & 15; }
                else if (u < 588)  { int x=u-140;  ent=14+(x>>6);  f = x & 63; }
                else if (u < 2380) { int x=u-588;  ent=21+(x>>8);  f = x & 255; }
                else if (u < 2828) { int x=u-2380; ent=28+(x>>4);  f = x & 15; }
                else if (u < 2884) { int x=u-2828; ent=56+(x>>1);  f = x & 1; }
                else               { int x=u-2884; ent=84+(x>>1);  f = x & 1; }
                unsigned long long a = bases_s[ent * MQ + q] + (unsigned long long)(f * 16);
                v = *(const float4*)(uintptr_t)a;
            }
            float r0 = fmaxf(v.x, 0.f), r1 = fmaxf(v.y, 0.f);
            float r2 = fmaxf(v.z, 0.f), r3 = fmaxf(v.w, 0.f);
            ss += r0*r0 + r1*r1 + r2*r2 + r3*r3;
            ushort4 pk;
            pk.x = f2bf(r0); pk.y = f2bf(r1); pk.z = f2bf(r2); pk.w = f2bf(r3);
            *(ushort4*)&Atile[q * ASTRIDE + e * 4] = pk;
        }
        // ---- stage W: Wt[64][k0..k0+256) -> LDS ----
        const int k0 = tile * KTILE;
        #pragma unroll
        for (int it2 = 0; it2 < 4; ++it2) {
            const int idx = it2 * NTHR + tid;              // [0,2048)
            const int j = idx >> 5, c = idx & 31;
            const int kg = k0 + c * 8;
            uint4 val = make_uint4(0u, 0u, 0u, 0u);
            if (kg < TOTF) val = *(const uint4*)(Wt + j * TOTF + kg);
            *(uint4*)&Wtile[j * ASTRIDE + c * 8] = val;
        }
        __syncthreads();
        // ---- MFMA: 4 K-steps of 32 per wave ----
        #pragma unroll
        for (int s2 = 0; s2 < 4; ++s2) {
            const int kk = (ksp * 4 + s2) * 32 + kq;
            bf16x8 av = *(const bf16x8*)&Atile[mrow * ASTRIDE + kk];
            bf16x8 bv = *(const bf16x8*)&Wtile[(jt * 16 + mrow) * ASTRIDE + kk];
            acc = __builtin_amdgcn_mfma_f32_16x16x32_bf16(av, bv, acc, 0, 0, 0);
        }
    }

    // ---- epilogue ----
    __syncthreads();                       // Atile free; reuse as h_s[16][64]
    atomicAdd(&ssq_s[q], ss);
    float* h_s = (float*)Atile;
    if (ksp == 0) {
        #pragma unroll
        for (int r = 0; r < 4; ++r)
            h_s[((lane >> 4) * 4 + r) * 64 + jt * 16 + (lane & 15)] = acc[r];
    }
    __syncthreads();
    if (ksp == 1) {
        #pragma unroll
        for (int r = 0; r < 4; ++r)
            h_s[((lane >> 4) * 4 + r) * 64 + jt * 16 + (lane & 15)] += acc[r];
    }
    __syncthreads();
    if (tid < MQ) {
        const float RSQ = 9.0395480320866816e-03f;   // 12240^-0.5
        inv_s[tid] = 1.0f / (sqrtf(ssq_s[tid]) * RSQ + 1e-8f);
    }
    __syncthreads();
    if (tid < 64) {
        const int qq = tid >> 2, o = tid & 3;
        const int qqg = q0 + qq;
        if (qqg < N) {
            const float inv = inv_s[qq];
            float s = b_final[o];
            float hs = 0.f;
            #pragma unroll 8
            for (int j = 0; j < 64; ++j)
                hs += fmaxf(h_s[qq * 64 + j], 0.f) * w_final[j * 4 + o];
            s += hs * inv;                            // relu(h*inv) = inv*relu(h), inv>0
            s += dirv[qqg*3+0] * w_final[64*4 + o];
            s += dirv[qqg*3+1] * w_final[65*4 + o];
            s += dirv[qqg*3+2] * w_final[66*4 + o];
            s += t[qqg]        * w_final[67*4 + o];
            out[qqg * 4 + o] = 1.0f / (1.0f + expf(-s));
        }
    }
}

extern "C" void kernel_launch(void* const* d_in, const int* in_sizes, int n_in,
                              void* d_out, int out_size, void* d_ws, size_t ws_size,
                              hipStream_t stream) {
    const float* pos  = (const float*)d_in[0];
    const float* dirv = (const float*)d_in[1];
    const float* t    = (const float*)d_in[2];
    const float* tb0  = (const float*)d_in[3];
    const float* tb1  = (const float*)d_in[4];
    const float* tb2  = (const float*)d_in[5];
    const float* tb3  = (const float*)d_in[6];
    const float* st1  = (const float*)d_in[7];
    const float* st2  = (const float*)d_in[8];
    const float* tf3  = (const float*)d_in[9];
    const float* rs   = (const float*)d_in[10];
    const float* wd   = (const float*)d_in[11];
    const float* wf   = (const float*)d_in[12];
    const float* bf   = (const float*)d_in[13];
    float* out = (float*)d_out;
    unsigned short* Wt = (unsigned short*)d_ws;      // 64*12240*2 = 1.57 MB

    const int N = in_sizes[2];                       // 8192
    wconv_kernel<<<dim3((TOTF * 64 + 255) / 256), dim3(256), 0, stream>>>(wd, rs, Wt);
    st_fused_kernel<<<dim3((N + MQ - 1) / MQ), dim3(NTHR), 0, stream>>>(
        pos, dirv, t, tb0, tb1, tb2, tb3, st1, st2, tf3, Wt, wf, bf, out, N);
}